// Round 4
// baseline (471.192 us; speedup 1.0000x reference)
//
#include <hip/hip_runtime.h>
#include <hip/hip_bf16.h>

typedef unsigned short u16;
typedef unsigned int   u32;

typedef __attribute__((ext_vector_type(8))) short bfrag;   // 8 bf16 (4 VGPRs)
typedef __attribute__((ext_vector_type(4))) float f32x4;   // MFMA acc

static __device__ __forceinline__ u16 f2bf(float f) {
    u32 u = __float_as_uint(f);
    return (u16)((u + 0x7fffu + ((u >> 16) & 1u)) >> 16);   // RNE
}
static __device__ __forceinline__ u32 pk2(float a, float b) {
    return (u32)f2bf(a) | ((u32)f2bf(b) << 16);
}
static __device__ __forceinline__ float bf2f(u16 h) {
    return __uint_as_float((u32)h << 16);
}

// ---------------- kernel 0: w_base [3,3,512,256] f32 -> wt [9][256co][512ci] bf16
__global__ __launch_bounds__(256) void prep_w_k(const float* __restrict__ wb,
                                                u16* __restrict__ wt)
{
    int i  = blockIdx.x * 256 + threadIdx.x;      // < 9*256*512 = 1179648
    int ci = i & 511;
    int co = (i >> 9) & 255;
    int pos = i >> 17;
    wt[i] = f2bf(wb[(size_t)((pos << 9) + ci) * 256 + co]);
}

// ---------------- fused conv(3x3,relu) + heads + sigmoid/mask/pack
// BM=128 pixels, BN=256 channels (all), BK=64. 512 threads = 8 waves (2M x 4N).
union Smem {
    struct { u16 A[128][72]; u16 B[256][72]; } kl;   // 55296 B (72 = 64+8 pad)
    u16   ft[256][128];                               // 65536 B: feat^T bf16, rotated
    float raw[128 * 45];                              // 23040 B: head logits
};

template<int WMODE>   // 0: wt precomputed in ws; 1: convert w_base in-kernel
__global__ __launch_bounds__(512) void fused_k(
    const float* __restrict__ data,   // [8,64,64,512] f32
    const u16*   __restrict__ wt,     // [9][256][512] bf16 (WMODE 0)
    const float* __restrict__ wb,     // [3,3,512,256] f32 (WMODE 1)
    const float* __restrict__ bb,     // [256]
    const float* __restrict__ wc,     // [256,9]
    const float* __restrict__ bc,     // [9]
    const float* __restrict__ wr,     // [256,36]
    const float* __restrict__ br,     // [36]
    float*       __restrict__ out)    // [32768,45] f32
{
    __shared__ Smem sm;

    int bid = blockIdx.x;                         // 256 blocks
    int wg  = ((bid & 7) << 5) | (bid >> 3);      // bijective XCD swizzle
    int pm0 = wg << 7;                            // pixel base

    int tid = threadIdx.x, lane = tid & 63, wid = tid >> 6;
    int wm = (wid >> 2) << 6, wn = (wid & 3) << 6;
    int fr = lane & 15, fg = lane >> 4;

    int ar = tid >> 2, ac = (tid & 3) << 4;       // A-stage: row, 16-f32 chunk
    int brw = tid >> 1, bcc = (tid & 1) << 5;     // B-stage: row, 32-u16 half-row

    f32x4 acc[4][4] = {};

    #pragma unroll 1
    for (int pos = 0; pos < 9; ++pos) {
        int dy = pos / 3 - 1, dx = pos % 3 - 1;
        int p  = pm0 + ar;
        int yy = ((p >> 6) & 63) + dy, xx = (p & 63) + dx;
        bool ok = (yy >= 0) && (yy < 64) && (xx >= 0) && (xx < 64);
        const float* abase = data +
            ((size_t)(((p >> 12) << 12) + (yy << 6) + xx) << 9) + ac;

        #pragma unroll 1
        for (int cb = 0; cb < 8; ++cb) {
            // ---- stage A: fp32 -> bf16 (zero-fill at borders), 16 cols/thread ----
            float4 v0, v1, v2, v3;
            if (ok) {
                const float4* s = (const float4*)(abase + (cb << 6));
                v0 = s[0]; v1 = s[1]; v2 = s[2]; v3 = s[3];
            } else {
                v0 = v1 = v2 = v3 = make_float4(0.f, 0.f, 0.f, 0.f);
            }
            {
                uint4* ad = (uint4*)&sm.kl.A[ar][ac];
                ad[0] = make_uint4(pk2(v0.x,v0.y), pk2(v0.z,v0.w),
                                   pk2(v1.x,v1.y), pk2(v1.z,v1.w));
                ad[1] = make_uint4(pk2(v2.x,v2.y), pk2(v2.z,v2.w),
                                   pk2(v3.x,v3.y), pk2(v3.z,v3.w));
            }
            // ---- stage B: full 32-u16 half-row per thread (4 x uint4) ----
            if (WMODE == 0) {
                const uint4* s = (const uint4*)(wt + (((size_t)pos) << 17) +
                                 ((size_t)brw << 9) + (cb << 6) + bcc);
                uint4* bd = (uint4*)&sm.kl.B[brw][bcc];
                bd[0] = s[0]; bd[1] = s[1]; bd[2] = s[2]; bd[3] = s[3];
            } else {
                int cow = (tid & 63) << 2;
                const float* wsrc = wb + ((size_t)(pos * 512 + (cb << 6))) * 256 + cow;
                #pragma unroll
                for (int pp = 0; pp < 8; ++pp) {
                    int cil = (pp << 3) + (tid >> 6);
                    float4 v = *(const float4*)(wsrc + cil * 256);
                    sm.kl.B[cow + 0][cil] = f2bf(v.x);
                    sm.kl.B[cow + 1][cil] = f2bf(v.y);
                    sm.kl.B[cow + 2][cil] = f2bf(v.z);
                    sm.kl.B[cow + 3][cil] = f2bf(v.w);
                }
            }
            __syncthreads();

            // ---- MFMA: 2 k-subtiles of 32 ----
            #pragma unroll
            for (int kk = 0; kk < 2; ++kk) {
                bfrag av[4], bv[4];
                #pragma unroll
                for (int i = 0; i < 4; ++i) {
                    av[i] = *(const bfrag*)&sm.kl.A[wm + (i << 4) + fr][(kk << 5) + (fg << 3)];
                    bv[i] = *(const bfrag*)&sm.kl.B[wn + (i << 4) + fr][(kk << 5) + (fg << 3)];
                }
                #pragma unroll
                for (int mi = 0; mi < 4; ++mi)
                    #pragma unroll
                    for (int ni = 0; ni < 4; ++ni)
                        acc[mi][ni] = __builtin_amdgcn_mfma_f32_16x16x32_bf16(
                            av[mi], bv[ni], acc[mi][ni], 0, 0, 0);
            }
            __syncthreads();
        }
    }

    // ---- epilogue: bias+relu -> ft[co][pix] bf16, rotation-swizzled ----
    #pragma unroll
    for (int ni = 0; ni < 4; ++ni) {
        int co = wn + (ni << 4) + fr;
        float bias = bb[co];
        int rot = (co & 31) << 2;
        #pragma unroll
        for (int mi = 0; mi < 4; ++mi) {
            int pb  = wm + (mi << 4) + (fg << 2);       // multiple of 4
            int col = (pb + rot) & 127;                 // stays 4-aligned
            float r0 = fmaxf(acc[mi][ni][0] + bias, 0.f);
            float r1 = fmaxf(acc[mi][ni][1] + bias, 0.f);
            float r2 = fmaxf(acc[mi][ni][2] + bias, 0.f);
            float r3 = fmaxf(acc[mi][ni][3] + bias, 0.f);
            *(uint2*)&sm.ft[co][col] = make_uint2(pk2(r0, r1), pk2(r2, r3));
        }
    }
    __syncthreads();

    // ---- head dot: wave w owns channels [6w, 6w+6); lanes = pixels (2 passes) ----
    int wchx = __builtin_amdgcn_readfirstlane(wid) * 6;
    float sv[2][6];
    #pragma unroll
    for (int pass = 0; pass < 2; ++pass) {
        int pix = lane + (pass << 6);
        float a6[6];
        #pragma unroll
        for (int j = 0; j < 6; ++j) {
            int ch = wchx + j;
            a6[j] = (ch < 36) ? br[ch] : ((ch < 45) ? bc[ch - 36] : 0.f);
        }
        #pragma unroll 4
        for (int c = 0; c < 256; ++c) {
            int col = (pix + ((c & 31) << 2)) & 127;    // undo rotation
            float f = bf2f(sm.ft[c][col]);
            #pragma unroll
            for (int j = 0; j < 6; ++j) {
                int ch = wchx + j;                      // wave-uniform -> s_load
                if (ch < 36)      a6[j] = fmaf(f, wr[c * 36 + ch], a6[j]);
                else if (ch < 45) a6[j] = fmaf(f, wc[c * 9 + ch - 36], a6[j]);
            }
        }
        #pragma unroll
        for (int j = 0; j < 6; ++j) sv[pass][j] = a6[j];
    }
    __syncthreads();   // all ft reads done before union reuse
    #pragma unroll
    for (int pass = 0; pass < 2; ++pass) {
        int pix = lane + (pass << 6);
        #pragma unroll
        for (int j = 0; j < 6; ++j) {
            int ch = wchx + j;
            if (ch < 45) sm.raw[pix * 45 + ch] = sv[pass][j];
        }
    }
    __syncthreads();

    // ---- final: sigmoid + mask + pack -> f32 out ----
    {
        int pix = tid >> 2, q = tid & 3;
        const float* rp = &sm.raw[pix * 45];
        float* op = out + (size_t)(pm0 + pix) * 45;
        int na = (q == 3) ? 3 : 2;
        int a0 = (q == 3) ? 6 : (q << 1);
        for (int t = 0; t < na; ++t) {
            int a = a0 + t;
            float lg  = rp[36 + a];
            float obj = 1.f / (1.f + __expf(-lg));
            float b0 = rp[4*a], b1 = rp[4*a+1], b2 = rp[4*a+2], b3 = rp[4*a+3];
            bool m = (obj > 0.7f) && (b2 > 10.f) && (b3 > 10.f);
            op[4*a    ] = m ? b0 : 0.f;
            op[4*a + 1] = m ? b1 : 0.f;
            op[4*a + 2] = m ? b2 : 0.f;
            op[4*a + 3] = m ? b3 : 0.f;
            op[36 + a ] = obj;
        }
    }
}

extern "C" void kernel_launch(void* const* d_in, const int* in_sizes, int n_in,
                              void* d_out, int out_size, void* d_ws, size_t ws_size,
                              hipStream_t stream)
{
    const float* data = (const float*)d_in[0];
    const float* wb   = (const float*)d_in[1];
    const float* bb   = (const float*)d_in[2];
    const float* wc   = (const float*)d_in[3];
    const float* bcl  = (const float*)d_in[4];
    const float* wr   = (const float*)d_in[5];
    const float* brg  = (const float*)d_in[6];
    float* out = (float*)d_out;

    const size_t WT_BYTES = (size_t)9 * 256 * 512 * 2;   // 2,359,296

    if (ws_size >= WT_BYTES) {
        u16* wt = (u16*)d_ws;
        prep_w_k<<<4608, 256, 0, stream>>>(wb, wt);
        fused_k<0><<<256, 512, 0, stream>>>(data, wt, wb, bb, wc, bcl, wr, brg, out);
    } else {
        fused_k<1><<<256, 512, 0, stream>>>(data, (const u16*)nullptr, wb,
                                            bb, wc, bcl, wr, brg, out);
    }
}